// Round 4
// baseline (580.593 us; speedup 1.0000x reference)
//
#include <hip/hip_runtime.h>
#include <hip/hip_bf16.h>

#define T_TOK 16384
#define H_DIM 1024
#define I_DIM 1024
#define E_NUM 8
#define NPAIR (T_TOK * 2)
#define BM 128
#define BM2 64
#define BK 64
#define MAX_MT (NPAIR / BM + E_NUM)     // 264 worst-case 128-row tiles
#define MAX_MT2 (NPAIR / BM2 + E_NUM)   // 520 worst-case 64-row tiles

typedef float v4f __attribute__((ext_vector_type(4)));
typedef float v16f __attribute__((ext_vector_type(16)));
typedef short v8s __attribute__((ext_vector_type(8)));

__device__ __forceinline__ unsigned short f2bf(float f) {
    unsigned int u = __float_as_uint(f);
    unsigned int r = (u + 0x7fffu + ((u >> 16) & 1u)) >> 16;   // RNE
    return (unsigned short)r;
}
__device__ __forceinline__ float bf2f(unsigned short s) {
    return __uint_as_float(((unsigned int)s) << 16);
}

__device__ __forceinline__ void gl_lds16(const void* g, void* l) {
    __builtin_amdgcn_global_load_lds(
        (const __attribute__((address_space(1))) void*)g,
        (__attribute__((address_space(3))) void*)l, 16, 0, 0);
}

// XOR-swizzled LDS tile: row-major [rows][64 bf16], each row's eight 16B units
// xor'd by (row&7). Staged by swizzling the GLOBAL source column per lane.
__device__ __forceinline__ int swz(int row, int unit) {
    return row * 64 + ((unit ^ (row & 7)) << 3);
}

// ---------------- routing ----------------
__global__ void k_route(const float* __restrict__ gating,
                        int* __restrict__ tokExp, float* __restrict__ tokW,
                        int* __restrict__ counts) {
    int t = blockIdx.x * 256 + threadIdx.x;
    int lane = threadIdx.x & 63;
    float g[E_NUM];
#pragma unroll
    for (int e = 0; e < E_NUM; e++) g[e] = gating[t * E_NUM + e];
    int i0 = 0; float v0 = g[0];
#pragma unroll
    for (int e = 1; e < E_NUM; e++) if (g[e] > v0) { v0 = g[e]; i0 = e; }
    int i1 = -1; float v1 = -1e30f;
#pragma unroll
    for (int e = 0; e < E_NUM; e++) if (e != i0 && g[e] > v1) { v1 = g[e]; i1 = e; }
    float w0 = 1.f / (1.f + __expf(v1 - v0));   // renormalized top-2
    tokExp[2 * t] = i0; tokExp[2 * t + 1] = i1;
    tokW[2 * t] = w0;   tokW[2 * t + 1] = 1.f - w0;
#pragma unroll
    for (int e = 0; e < E_NUM; e++) {
        unsigned long long mA = __ballot(i0 == e);
        unsigned long long mB = __ballot(i1 == e);
        int c = __popcll(mA) + __popcll(mB);
        if (lane == 0 && c) atomicAdd(&counts[e], c);
    }
}

__global__ void k_scan(const int* __restrict__ counts, int* __restrict__ offsets,
                       int* __restrict__ tileOff, int* __restrict__ tileOff2,
                       int* __restrict__ cursor) {
    if (threadIdx.x == 0 && blockIdx.x == 0) {
        int o = 0, to = 0, to2 = 0;
        for (int e = 0; e < E_NUM; e++) {
            offsets[e] = o; tileOff[e] = to; tileOff2[e] = to2; cursor[e] = o;
            o += counts[e];
            to += (counts[e] + BM - 1) / BM;
            to2 += (counts[e] + BM2 - 1) / BM2;
        }
        offsets[E_NUM] = o; tileOff[E_NUM] = to; tileOff2[E_NUM] = to2;
    }
}

__global__ void k_scatter(const int* __restrict__ tokExp, const float* __restrict__ tokW,
                          int* __restrict__ cursor,
                          int* __restrict__ pairTok, float* __restrict__ pairW,
                          int* __restrict__ invMap) {
    int t = blockIdx.x * 256 + threadIdx.x;
    int lane = threadIdx.x & 63;
#pragma unroll
    for (int k = 0; k < 2; k++) {
        int e = tokExp[2 * t + k];
        int pos = 0;
#pragma unroll
        for (int ex = 0; ex < E_NUM; ex++) {
            unsigned long long m = __ballot(e == ex);
            if (m) {
                int leader = __builtin_ctzll(m);
                int base = 0;
                if (lane == leader) base = atomicAdd(&cursor[ex], __popcll(m));
                base = __shfl(base, leader);
                if (e == ex) pos = base + __popcll(m & ((1ull << lane) - 1ull));
            }
        }
        pairTok[pos] = t;
        pairW[pos] = tokW[2 * t + k];
        invMap[2 * t + k] = pos;
    }
}

// ---------------- conversions ----------------
__global__ void k_cvt_x(const float* __restrict__ src, unsigned short* __restrict__ dst) {
    size_t i4 = ((size_t)blockIdx.x * 256 + threadIdx.x) * 4;
    float4 v = *(const float4*)(src + i4);
    ushort4 o;
    o.x = f2bf(v.x); o.y = f2bf(v.y); o.z = f2bf(v.z); o.w = f2bf(v.w);
    *(ushort4*)(dst + i4) = o;
}

__global__ void k_cvt_w(const float* __restrict__ src, unsigned short* __restrict__ dst,
                        const float* __restrict__ scale, int shift) {
    size_t i4 = ((size_t)blockIdx.x * 256 + threadIdx.x) * 4;
    float s = scale[i4 >> shift];
    float4 v = *(const float4*)(src + i4);
    ushort4 o;
    o.x = f2bf(v.x * s); o.y = f2bf(v.y * s); o.z = f2bf(v.z * s); o.w = f2bf(v.w * s);
    *(ushort4*)(dst + i4) = o;
}

// ---------------- GEMM1: h = silu(x@Wg^T) * (x@Wu^T), gathered rows ----------------
// block 256 thr (4 waves). tile: 128 rows x 64 h-cols x {gate,up}. K=1024.
// wave = 64 rows x 64 cols x ONE role (waves 0,1 gate / 2,3 up): acc 2x2x16 = 64 regs.
// Epilogue: up-waves pass results through LDS; gate-waves fuse silu*up.
__global__ __launch_bounds__(256, 3)
void k_gemm1(const unsigned short* __restrict__ xbf,   // [T][H] bf16
             const unsigned short* __restrict__ w1bf,  // [E][2I][H] bf16 (dequant)
             const int* __restrict__ pairTok,
             const int* __restrict__ offsets, const int* __restrict__ tileOff,
             unsigned short* __restrict__ hbuf) {      // [NPAIR][I] bf16
    __shared__ unsigned short lA[BM * BK];             // 16 KB
    __shared__ unsigned short lB[BM * BK];             // 16 KB: rows 0-63 gate, 64-127 up

    int mt = blockIdx.x;
    if (mt >= tileOff[E_NUM]) return;
    int e = 0;
    while (mt >= tileOff[e + 1]) e++;
    int row0 = offsets[e] + (mt - tileOff[e]) * BM;
    int valid = offsets[e + 1] - row0; if (valid > BM) valid = BM;

    int nt = blockIdx.y;                 // 0..15, 64 h-cols per block
    int tid = threadIdx.x;
    int lane = tid & 63, wave = tid >> 6;
    int wm = wave & 1, role = wave >> 1; // role 0 = gate, 1 = up

    int lr = lane >> 3;
    int lcs = ((lane & 7) ^ lr) * 8;     // swizzled global col (bf16 units)

    const unsigned short* wg = w1bf + (size_t)e * 2 * I_DIM * H_DIM + (size_t)(nt * 64) * H_DIM;
    const unsigned short* wu = wg + (size_t)I_DIM * H_DIM;
    const unsigned short* bsrc = (wave & 2) ? wu : wg;

    int tokRow[4];
#pragma unroll
    for (int j = 0; j < 4; j++) {
        int r = wave * 32 + j * 8 + lr;
        int rc = r < valid ? r : valid - 1;
        tokRow[j] = pairTok[row0 + rc];
    }

    v16f acc[2][2];
#pragma unroll
    for (int i = 0; i < 2; i++)
#pragma unroll
        for (int j = 0; j < 2; j++) acc[i][j] = (v16f)0.f;

    for (int ko = 0; ko < H_DIM / BK; ko++) {
        int k0 = ko * BK;
        __syncthreads();
#pragma unroll
        for (int j = 0; j < 4; j++)      // A: 4 chunks/wave = 128 rows total
            gl_lds16(xbf + (size_t)tokRow[j] * H_DIM + k0 + lcs, lA + (wave * 4 + j) * 512);
#pragma unroll
        for (int j = 0; j < 4; j++) {    // B: 4 chunks/wave = 128 rows (64 gate + 64 up)
            int srcrow = (wave & 1) * 32 + j * 8 + lr;
            gl_lds16(bsrc + (size_t)srcrow * H_DIM + k0 + lcs, lB + (wave * 4 + j) * 512);
        }
        __syncthreads();
#pragma unroll
        for (int kk = 0; kk < BK; kk += 16) {
            int u = (kk >> 3) + (lane >> 5);
            v8s a[2], b[2];
#pragma unroll
            for (int i = 0; i < 2; i++)
                a[i] = *(const v8s*)(lA + swz(wm * 64 + i * 32 + (lane & 31), u));
#pragma unroll
            for (int j = 0; j < 2; j++)
                b[j] = *(const v8s*)(lB + swz(role * 64 + j * 32 + (lane & 31), u));
#pragma unroll
            for (int i = 0; i < 2; i++)
#pragma unroll
                for (int j = 0; j < 2; j++)
                    acc[i][j] = __builtin_amdgcn_mfma_f32_32x32x16_bf16(a[i], b[j], acc[i][j], 0, 0, 0);
        }
    }

    int half = lane >> 5, c = lane & 31;
    __syncthreads();
    if (role == 1) {                     // up-waves: deposit u into lB (128 x 64 bf16)
#pragma unroll
        for (int i = 0; i < 2; i++)
#pragma unroll
            for (int r = 0; r < 16; r++) {
                int row = wm * 64 + i * 32 + (r & 3) + 8 * (r >> 2) + 4 * half;
#pragma unroll
                for (int j = 0; j < 2; j++)
                    lB[row * 64 + j * 32 + c] = f2bf(acc[i][j][r]);
            }
    }
    __syncthreads();
    if (role == 0) {                     // gate-waves: silu(g) * u -> hbuf
#pragma unroll
        for (int i = 0; i < 2; i++)
#pragma unroll
            for (int r = 0; r < 16; r++) {
                int row = wm * 64 + i * 32 + (r & 3) + 8 * (r >> 2) + 4 * half;
                if (row < valid) {
                    size_t base = (size_t)(row0 + row) * I_DIM + nt * 64;
#pragma unroll
                    for (int j = 0; j < 2; j++) {
                        float g = acc[i][j][r];
                        float uu = bf2f(lB[row * 64 + j * 32 + c]);
                        float s = g / (1.f + __expf(-g));
                        hbuf[base + j * 32 + c] = f2bf(s * uu);
                    }
                }
            }
    }
}

// ---------------- GEMM2: ybuf[pos] = coef * (h[pos] @ W2^T), bf16 ----------------
// block 256 thr (4 waves 2x2). tile: 64 rows x 256 out-cols. wave 32x128, acc 4x16=64.
__global__ __launch_bounds__(256, 3)
void k_gemm2(const unsigned short* __restrict__ hbuf,  // [NPAIR][I]
             const unsigned short* __restrict__ w2bf,  // [E][H][I] bf16 (dequant)
             const float* __restrict__ pairW,
             const int* __restrict__ offsets, const int* __restrict__ tileOff2,
             unsigned short* __restrict__ ybuf) {      // [NPAIR][H] bf16
    __shared__ unsigned short lA[BM2 * BK];            // 8 KB
    __shared__ unsigned short lB[256 * BK];            // 32 KB

    int mt = blockIdx.x;
    if (mt >= tileOff2[E_NUM]) return;
    int e = 0;
    while (mt >= tileOff2[e + 1]) e++;
    int row0 = offsets[e] + (mt - tileOff2[e]) * BM2;
    int valid = offsets[e + 1] - row0; if (valid > BM2) valid = BM2;

    int nt = blockIdx.y;                 // 0..3, 256 out-cols per block
    int tid = threadIdx.x;
    int lane = tid & 63, wave = tid >> 6;
    int wm = wave & 1, wn = wave >> 1;

    int lr = lane >> 3;
    int lcs = ((lane & 7) ^ lr) * 8;

    const unsigned short* w2e = w2bf + (size_t)e * H_DIM * I_DIM + (size_t)(nt * 256) * I_DIM;

    int rowA[2];
#pragma unroll
    for (int j = 0; j < 2; j++) {
        int r = wave * 16 + j * 8 + lr;
        int rc = r < valid ? r : valid - 1;
        rowA[j] = row0 + rc;
    }

    v16f acc[4];
#pragma unroll
    for (int j = 0; j < 4; j++) acc[j] = (v16f)0.f;

    for (int ko = 0; ko < I_DIM / BK; ko++) {
        int k0 = ko * BK;
        __syncthreads();
#pragma unroll
        for (int j = 0; j < 2; j++)      // A: 2 chunks/wave = 64 rows
            gl_lds16(hbuf + (size_t)rowA[j] * I_DIM + k0 + lcs, lA + (wave * 2 + j) * 512);
#pragma unroll
        for (int j = 0; j < 8; j++)      // B: 8 chunks/wave = 256 rows
            gl_lds16(w2e + (size_t)(wave * 64 + j * 8 + lr) * I_DIM + k0 + lcs,
                     lB + (wave * 8 + j) * 512);
        __syncthreads();
#pragma unroll
        for (int kk = 0; kk < BK; kk += 16) {
            int u = (kk >> 3) + (lane >> 5);
            v8s a = *(const v8s*)(lA + swz(wm * 32 + (lane & 31), u));
            v8s b[4];
#pragma unroll
            for (int j = 0; j < 4; j++)
                b[j] = *(const v8s*)(lB + swz(wn * 128 + j * 32 + (lane & 31), u));
#pragma unroll
            for (int j = 0; j < 4; j++)
                acc[j] = __builtin_amdgcn_mfma_f32_32x32x16_bf16(a, b[j], acc[j], 0, 0, 0);
        }
    }

    int half = lane >> 5, c = lane & 31;
#pragma unroll
    for (int r = 0; r < 16; r++) {
        int row = wm * 32 + (r & 3) + 8 * (r >> 2) + 4 * half;
        if (row < valid) {
            int pos = row0 + row;
            float coef = pairW[pos];
            unsigned short* orow = ybuf + (size_t)pos * H_DIM + nt * 256 + wn * 128;
#pragma unroll
            for (int j = 0; j < 4; j++)
                orow[j * 32 + c] = f2bf(coef * acc[j][r]);
        }
    }
}

// ---------------- reduce: out[t] = ybuf[pair0(t)] + ybuf[pair1(t)] ----------------
__global__ __launch_bounds__(256)
void k_reduce(const unsigned short* __restrict__ ybuf,
              const int* __restrict__ invMap,
              float* __restrict__ out) {
    int t = blockIdx.x;
    int p0 = invMap[2 * t], p1 = invMap[2 * t + 1];
    int c4 = threadIdx.x * 4;
    ushort4 a = *(const ushort4*)(ybuf + (size_t)p0 * H_DIM + c4);
    ushort4 b = *(const ushort4*)(ybuf + (size_t)p1 * H_DIM + c4);
    float4 o;
    o.x = bf2f(a.x) + bf2f(b.x);
    o.y = bf2f(a.y) + bf2f(b.y);
    o.z = bf2f(a.z) + bf2f(b.z);
    o.w = bf2f(a.w) + bf2f(b.w);
    *(float4*)(out + (size_t)t * H_DIM + c4) = o;
}

extern "C" void kernel_launch(void* const* d_in, const int* in_sizes, int n_in,
                              void* d_out, int out_size, void* d_ws, size_t ws_size,
                              hipStream_t stream) {
    const float* x      = (const float*)d_in[0];
    const float* gating = (const float*)d_in[1];
    const float* w1     = (const float*)d_in[2];
    const float* w2     = (const float*)d_in[3];
    const float* w1s    = (const float*)d_in[4];
    const float* w2s    = (const float*)d_in[5];
    float* out = (float*)d_out;

    char* ws = (char*)d_ws;
    size_t off = 0;
    auto alloc = [&](size_t bytes) { void* p = ws + off; off += (bytes + 255) & ~(size_t)255; return p; };
    unsigned short* xbf  = (unsigned short*)alloc((size_t)T_TOK * H_DIM * 2);             // 32 MB
    unsigned short* w1bf = (unsigned short*)alloc((size_t)E_NUM * 2 * I_DIM * H_DIM * 2); // 32 MB
    unsigned short* w2bf = (unsigned short*)alloc((size_t)E_NUM * H_DIM * I_DIM * 2);     // 16 MB
    unsigned short* hbuf = (unsigned short*)alloc((size_t)NPAIR * I_DIM * 2);             // 64 MB
    unsigned short* ybuf = (unsigned short*)alloc((size_t)NPAIR * H_DIM * 2);             // 64 MB
    int*   pairTok  = (int*)alloc(NPAIR * 4);
    float* pairW    = (float*)alloc(NPAIR * 4);
    int*   tokExp   = (int*)alloc(NPAIR * 4);
    float* tokW     = (float*)alloc(NPAIR * 4);
    int*   invMap   = (int*)alloc(NPAIR * 4);
    int*   counts   = (int*)alloc(64);
    int*   offsets  = (int*)alloc(64);
    int*   tileOff  = (int*)alloc(64);
    int*   tileOff2 = (int*)alloc(64);
    int*   cursor   = (int*)alloc(64);

    hipMemsetAsync(counts, 0, 64, stream);

    k_route<<<T_TOK / 256, 256, 0, stream>>>(gating, tokExp, tokW, counts);
    k_scan<<<1, 64, 0, stream>>>(counts, offsets, tileOff, tileOff2, cursor);
    k_scatter<<<T_TOK / 256, 256, 0, stream>>>(tokExp, tokW, cursor, pairTok, pairW, invMap);
    k_cvt_x<<<(T_TOK * H_DIM / 4) / 256, 256, 0, stream>>>(x, xbf);
    k_cvt_w<<<(E_NUM * 2 * I_DIM * H_DIM / 4) / 256, 256, 0, stream>>>(w1, w1bf, w1s, 21);
    k_cvt_w<<<(E_NUM * H_DIM * I_DIM / 4) / 256, 256, 0, stream>>>(w2, w2bf, w2s, 20);

    dim3 g1(MAX_MT, I_DIM / 64);          // 264 x 16
    k_gemm1<<<g1, 256, 0, stream>>>(xbf, w1bf, pairTok, offsets, tileOff, hbuf);
    dim3 g2(MAX_MT2, H_DIM / 256);        // 520 x 4
    k_gemm2<<<g2, 256, 0, stream>>>(hbuf, w2bf, pairW, offsets, tileOff2, ybuf);
    k_reduce<<<T_TOK, 256, 0, stream>>>(ybuf, invMap, out);
}

// Round 5
// 561.119 us; speedup vs baseline: 1.0347x; 1.0347x over previous
//
#include <hip/hip_runtime.h>
#include <hip/hip_bf16.h>

#define T_TOK 16384
#define H_DIM 1024
#define I_DIM 1024
#define E_NUM 8
#define NPAIR (T_TOK * 2)
#define BM 128
#define BK 64
#define MAX_MT (NPAIR / BM + E_NUM)     // 264 worst-case 128-row tiles

typedef float v4f __attribute__((ext_vector_type(4)));
typedef float v16f __attribute__((ext_vector_type(16)));
typedef short v8s __attribute__((ext_vector_type(8)));

__device__ __forceinline__ unsigned short f2bf(float f) {
    unsigned int u = __float_as_uint(f);
    unsigned int r = (u + 0x7fffu + ((u >> 16) & 1u)) >> 16;   // RNE
    return (unsigned short)r;
}
__device__ __forceinline__ float bf2f(unsigned short s) {
    return __uint_as_float(((unsigned int)s) << 16);
}

__device__ __forceinline__ void gl_lds16(const void* g, void* l) {
    __builtin_amdgcn_global_load_lds(
        (const __attribute__((address_space(1))) void*)g,
        (__attribute__((address_space(3))) void*)l, 16, 0, 0);
}

// XOR-swizzled LDS tile: row-major [rows][64 bf16], each row's eight 16B units
// xor'd by (row&7). Staged by swizzling the GLOBAL source column per lane.
__device__ __forceinline__ int swz(int row, int unit) {
    return row * 64 + ((unit ^ (row & 7)) << 3);
}

// ---------------- routing ----------------
__global__ void k_route(const float* __restrict__ gating,
                        int* __restrict__ tokExp, float* __restrict__ tokW,
                        int* __restrict__ counts) {
    int t = blockIdx.x * 256 + threadIdx.x;
    int lane = threadIdx.x & 63;
    float g[E_NUM];
#pragma unroll
    for (int e = 0; e < E_NUM; e++) g[e] = gating[t * E_NUM + e];
    int i0 = 0; float v0 = g[0];
#pragma unroll
    for (int e = 1; e < E_NUM; e++) if (g[e] > v0) { v0 = g[e]; i0 = e; }
    int i1 = -1; float v1 = -1e30f;
#pragma unroll
    for (int e = 0; e < E_NUM; e++) if (e != i0 && g[e] > v1) { v1 = g[e]; i1 = e; }
    float w0 = 1.f / (1.f + __expf(v1 - v0));   // renormalized top-2
    tokExp[2 * t] = i0; tokExp[2 * t + 1] = i1;
    tokW[2 * t] = w0;   tokW[2 * t + 1] = 1.f - w0;
#pragma unroll
    for (int e = 0; e < E_NUM; e++) {
        unsigned long long mA = __ballot(i0 == e);
        unsigned long long mB = __ballot(i1 == e);
        int c = __popcll(mA) + __popcll(mB);
        if (lane == 0 && c) atomicAdd(&counts[e], c);
    }
}

__global__ void k_scan(const int* __restrict__ counts, int* __restrict__ offsets,
                       int* __restrict__ tileOff, int* __restrict__ cursor) {
    if (threadIdx.x == 0 && blockIdx.x == 0) {
        int o = 0, to = 0;
        for (int e = 0; e < E_NUM; e++) {
            offsets[e] = o; tileOff[e] = to; cursor[e] = o;
            o += counts[e];
            to += (counts[e] + BM - 1) / BM;
        }
        offsets[E_NUM] = o; tileOff[E_NUM] = to;
    }
}

__global__ void k_scatter(const int* __restrict__ tokExp, const float* __restrict__ tokW,
                          int* __restrict__ cursor,
                          int* __restrict__ pairTok, float* __restrict__ pairW,
                          int* __restrict__ invMap) {
    int t = blockIdx.x * 256 + threadIdx.x;
    int lane = threadIdx.x & 63;
#pragma unroll
    for (int k = 0; k < 2; k++) {
        int e = tokExp[2 * t + k];
        int pos = 0;
#pragma unroll
        for (int ex = 0; ex < E_NUM; ex++) {
            unsigned long long m = __ballot(e == ex);
            if (m) {
                int leader = __builtin_ctzll(m);
                int base = 0;
                if (lane == leader) base = atomicAdd(&cursor[ex], __popcll(m));
                base = __shfl(base, leader);
                if (e == ex) pos = base + __popcll(m & ((1ull << lane) - 1ull));
            }
        }
        pairTok[pos] = t;
        pairW[pos] = tokW[2 * t + k];
        invMap[2 * t + k] = pos;
    }
}

// ---------------- conversions ----------------
__global__ void k_cvt_x(const float* __restrict__ src, unsigned short* __restrict__ dst) {
    size_t i4 = ((size_t)blockIdx.x * 256 + threadIdx.x) * 4;
    float4 v = *(const float4*)(src + i4);
    ushort4 o;
    o.x = f2bf(v.x); o.y = f2bf(v.y); o.z = f2bf(v.z); o.w = f2bf(v.w);
    *(ushort4*)(dst + i4) = o;
}

__global__ void k_cvt_w(const float* __restrict__ src, unsigned short* __restrict__ dst,
                        const float* __restrict__ scale, int shift) {
    size_t i4 = ((size_t)blockIdx.x * 256 + threadIdx.x) * 4;
    float s = scale[i4 >> shift];
    float4 v = *(const float4*)(src + i4);
    ushort4 o;
    o.x = f2bf(v.x * s); o.y = f2bf(v.y * s); o.z = f2bf(v.z * s); o.w = f2bf(v.w * s);
    *(ushort4*)(dst + i4) = o;
}

// ---------------- GEMM1: h = silu(x@Wg^T) * (x@Wu^T), gathered rows ----------------
// block 512 thr (8 waves). tile: 128 rows x 128 h-cols x {gate,up}. K=1024.
// waves 0-3 gate, 4-7 up; each wave 64x64, acc 2x2x16 = 64 regs.
// Epilogue: up-waves deposit u into lB; gate-waves fuse silu(g)*u.
__global__ __launch_bounds__(512, 4)
void k_gemm1(const unsigned short* __restrict__ xbf,   // [T][H] bf16
             const unsigned short* __restrict__ w1bf,  // [E][2I][H] bf16 (dequant)
             const int* __restrict__ pairTok,
             const int* __restrict__ offsets, const int* __restrict__ tileOff,
             unsigned short* __restrict__ hbuf) {      // [NPAIR][I] bf16
    __shared__ unsigned short lA[BM * BK];             // 16 KB
    __shared__ unsigned short lB[256 * BK];            // 32 KB: rows 0-127 gate, 128-255 up

    int mt = blockIdx.x;
    if (mt >= tileOff[E_NUM]) return;
    int e = 0;
    while (mt >= tileOff[e + 1]) e++;
    int row0 = offsets[e] + (mt - tileOff[e]) * BM;
    int valid = offsets[e + 1] - row0; if (valid > BM) valid = BM;

    int nt = blockIdx.y;                 // 0..7, 128 h-cols per block
    int tid = threadIdx.x;
    int lane = tid & 63, wave = tid >> 6;      // wave 0..7
    int role = wave >> 2, quad = wave & 3;     // role 0 = gate, 1 = up
    int wm = quad >> 1, wn = quad & 1;

    int lr = lane >> 3;
    int lcs = ((lane & 7) ^ lr) * 8;     // swizzled global col (bf16 units)

    const unsigned short* wg = w1bf + (size_t)e * 2 * I_DIM * H_DIM + (size_t)(nt * 128) * H_DIM;
    const unsigned short* wu = wg + (size_t)I_DIM * H_DIM;

    int tokRow[2];
#pragma unroll
    for (int j = 0; j < 2; j++) {
        int r = wave * 16 + j * 8 + lr;
        int rc = r < valid ? r : valid - 1;
        tokRow[j] = pairTok[row0 + rc];
    }
    const unsigned short* bRow[4];
#pragma unroll
    for (int j = 0; j < 4; j++) {
        int brow = wave * 32 + j * 8 + lr;     // 0..255
        bRow[j] = (brow < 128) ? (wg + (size_t)brow * H_DIM)
                               : (wu + (size_t)(brow - 128) * H_DIM);
    }

    v16f acc[2][2];
#pragma unroll
    for (int i = 0; i < 2; i++)
#pragma unroll
        for (int j = 0; j < 2; j++) acc[i][j] = (v16f)0.f;

    for (int ko = 0; ko < H_DIM / BK; ko++) {
        int k0 = ko * BK;
        __syncthreads();
#pragma unroll
        for (int j = 0; j < 2; j++)      // A: 2 chunks/wave = 128 rows total
            gl_lds16(xbf + (size_t)tokRow[j] * H_DIM + k0 + lcs, lA + (wave * 2 + j) * 512);
#pragma unroll
        for (int j = 0; j < 4; j++)      // B: 4 chunks/wave = 256 rows total
            gl_lds16(bRow[j] + k0 + lcs, lB + (wave * 4 + j) * 512);
        __syncthreads();
#pragma unroll
        for (int kk = 0; kk < BK; kk += 16) {
            int u = (kk >> 3) + (lane >> 5);
            v8s a[2], b[2];
#pragma unroll
            for (int i = 0; i < 2; i++)
                a[i] = *(const v8s*)(lA + swz(wm * 64 + i * 32 + (lane & 31), u));
#pragma unroll
            for (int j = 0; j < 2; j++)
                b[j] = *(const v8s*)(lB + swz(role * 128 + wn * 64 + j * 32 + (lane & 31), u));
#pragma unroll
            for (int i = 0; i < 2; i++)
#pragma unroll
                for (int j = 0; j < 2; j++)
                    acc[i][j] = __builtin_amdgcn_mfma_f32_32x32x16_bf16(a[i], b[j], acc[i][j], 0, 0, 0);
        }
    }

    int half = lane >> 5, c = lane & 31;
    __syncthreads();
    if (role == 1) {                     // up-waves: deposit u into lB as [128][128] bf16
#pragma unroll
        for (int i = 0; i < 2; i++)
#pragma unroll
            for (int r = 0; r < 16; r++) {
                int row = wm * 64 + i * 32 + (r & 3) + 8 * (r >> 2) + 4 * half;
#pragma unroll
                for (int j = 0; j < 2; j++)
                    lB[row * 128 + wn * 64 + j * 32 + c] = f2bf(acc[i][j][r]);
            }
    }
    __syncthreads();
    if (role == 0) {                     // gate-waves: silu(g) * u -> hbuf
#pragma unroll
        for (int i = 0; i < 2; i++)
#pragma unroll
            for (int r = 0; r < 16; r++) {
                int row = wm * 64 + i * 32 + (r & 3) + 8 * (r >> 2) + 4 * half;
                if (row < valid) {
                    size_t base = (size_t)(row0 + row) * I_DIM + nt * 128;
#pragma unroll
                    for (int j = 0; j < 2; j++) {
                        float g = acc[i][j][r];
                        float uu = bf2f(lB[row * 128 + wn * 64 + j * 32 + c]);
                        float s = g / (1.f + __expf(-g));
                        hbuf[base + wn * 64 + j * 32 + c] = f2bf(s * uu);
                    }
                }
            }
    }
}

// ---------------- GEMM2: ybuf[pos] = coef * (h[pos] @ W2^T), bf16 ----------------
// block 512 thr (8 waves, 2x4). tile: 128 rows x 256 out-cols. wave 64x64, acc 64.
__global__ __launch_bounds__(512, 4)
void k_gemm2(const unsigned short* __restrict__ hbuf,  // [NPAIR][I]
             const unsigned short* __restrict__ w2bf,  // [E][H][I] bf16 (dequant)
             const float* __restrict__ pairW,
             const int* __restrict__ offsets, const int* __restrict__ tileOff,
             unsigned short* __restrict__ ybuf) {      // [NPAIR][H] bf16
    __shared__ unsigned short lA[BM * BK];             // 16 KB
    __shared__ unsigned short lB[256 * BK];            // 32 KB

    int mt = blockIdx.x;
    if (mt >= tileOff[E_NUM]) return;
    int e = 0;
    while (mt >= tileOff[e + 1]) e++;
    int row0 = offsets[e] + (mt - tileOff[e]) * BM;
    int valid = offsets[e + 1] - row0; if (valid > BM) valid = BM;

    int nt = blockIdx.y;                 // 0..3, 256 out-cols per block
    int tid = threadIdx.x;
    int lane = tid & 63, wave = tid >> 6;
    int wm = wave >> 2, wn = wave & 3;   // 2 x 4 wave grid

    int lr = lane >> 3;
    int lcs = ((lane & 7) ^ lr) * 8;

    const unsigned short* w2e = w2bf + (size_t)e * H_DIM * I_DIM + (size_t)(nt * 256) * I_DIM;

    int rowA[2];
#pragma unroll
    for (int j = 0; j < 2; j++) {
        int r = wave * 16 + j * 8 + lr;
        int rc = r < valid ? r : valid - 1;
        rowA[j] = row0 + rc;
    }

    v16f acc[2][2];
#pragma unroll
    for (int i = 0; i < 2; i++)
#pragma unroll
        for (int j = 0; j < 2; j++) acc[i][j] = (v16f)0.f;

    for (int ko = 0; ko < I_DIM / BK; ko++) {
        int k0 = ko * BK;
        __syncthreads();
#pragma unroll
        for (int j = 0; j < 2; j++)      // A: 2 chunks/wave = 128 rows
            gl_lds16(hbuf + (size_t)rowA[j] * I_DIM + k0 + lcs, lA + (wave * 2 + j) * 512);
#pragma unroll
        for (int j = 0; j < 4; j++)      // B: 4 chunks/wave = 256 rows
            gl_lds16(w2e + (size_t)(wave * 32 + j * 8 + lr) * I_DIM + k0 + lcs,
                     lB + (wave * 4 + j) * 512);
        __syncthreads();
#pragma unroll
        for (int kk = 0; kk < BK; kk += 16) {
            int u = (kk >> 3) + (lane >> 5);
            v8s a[2], b[2];
#pragma unroll
            for (int i = 0; i < 2; i++)
                a[i] = *(const v8s*)(lA + swz(wm * 64 + i * 32 + (lane & 31), u));
#pragma unroll
            for (int j = 0; j < 2; j++)
                b[j] = *(const v8s*)(lB + swz(wn * 64 + j * 32 + (lane & 31), u));
#pragma unroll
            for (int i = 0; i < 2; i++)
#pragma unroll
                for (int j = 0; j < 2; j++)
                    acc[i][j] = __builtin_amdgcn_mfma_f32_32x32x16_bf16(a[i], b[j], acc[i][j], 0, 0, 0);
        }
    }

    int half = lane >> 5, c = lane & 31;
#pragma unroll
    for (int i = 0; i < 2; i++)
#pragma unroll
        for (int r = 0; r < 16; r++) {
            int row = wm * 64 + i * 32 + (r & 3) + 8 * (r >> 2) + 4 * half;
            if (row < valid) {
                int pos = row0 + row;
                float coef = pairW[pos];
                unsigned short* orow = ybuf + (size_t)pos * H_DIM + nt * 256;
#pragma unroll
                for (int j = 0; j < 2; j++)
                    orow[wn * 64 + j * 32 + c] = f2bf(coef * acc[i][j][r]);
            }
        }
}

// ---------------- reduce: out[t] = ybuf[pair0(t)] + ybuf[pair1(t)] ----------------
__global__ __launch_bounds__(256)
void k_reduce(const unsigned short* __restrict__ ybuf,
              const int* __restrict__ invMap,
              float* __restrict__ out) {
    int t = blockIdx.x;
    int p0 = invMap[2 * t], p1 = invMap[2 * t + 1];
    int c4 = threadIdx.x * 4;
    ushort4 a = *(const ushort4*)(ybuf + (size_t)p0 * H_DIM + c4);
    ushort4 b = *(const ushort4*)(ybuf + (size_t)p1 * H_DIM + c4);
    float4 o;
    o.x = bf2f(a.x) + bf2f(b.x);
    o.y = bf2f(a.y) + bf2f(b.y);
    o.z = bf2f(a.z) + bf2f(b.z);
    o.w = bf2f(a.w) + bf2f(b.w);
    *(float4*)(out + (size_t)t * H_DIM + c4) = o;
}

extern "C" void kernel_launch(void* const* d_in, const int* in_sizes, int n_in,
                              void* d_out, int out_size, void* d_ws, size_t ws_size,
                              hipStream_t stream) {
    const float* x      = (const float*)d_in[0];
    const float* gating = (const float*)d_in[1];
    const float* w1     = (const float*)d_in[2];
    const float* w2     = (const float*)d_in[3];
    const float* w1s    = (const float*)d_in[4];
    const float* w2s    = (const float*)d_in[5];
    float* out = (float*)d_out;

    char* ws = (char*)d_ws;
    size_t off = 0;
    auto alloc = [&](size_t bytes) { void* p = ws + off; off += (bytes + 255) & ~(size_t)255; return p; };
    unsigned short* xbf  = (unsigned short*)alloc((size_t)T_TOK * H_DIM * 2);             // 32 MB
    unsigned short* w1bf = (unsigned short*)alloc((size_t)E_NUM * 2 * I_DIM * H_DIM * 2); // 32 MB
    unsigned short* w2bf = (unsigned short*)alloc((size_t)E_NUM * H_DIM * I_DIM * 2);     // 16 MB
    unsigned short* hbuf = (unsigned short*)alloc((size_t)NPAIR * I_DIM * 2);             // 64 MB
    unsigned short* ybuf = (unsigned short*)alloc((size_t)NPAIR * H_DIM * 2);             // 64 MB
    int*   pairTok  = (int*)alloc(NPAIR * 4);
    float* pairW    = (float*)alloc(NPAIR * 4);
    int*   tokExp   = (int*)alloc(NPAIR * 4);
    float* tokW     = (float*)alloc(NPAIR * 4);
    int*   invMap   = (int*)alloc(NPAIR * 4);
    int*   counts   = (int*)alloc(64);
    int*   offsets  = (int*)alloc(64);
    int*   tileOff  = (int*)alloc(64);
    int*   cursor   = (int*)alloc(64);

    hipMemsetAsync(counts, 0, 64, stream);

    k_route<<<T_TOK / 256, 256, 0, stream>>>(gating, tokExp, tokW, counts);
    k_scan<<<1, 64, 0, stream>>>(counts, offsets, tileOff, cursor);
    k_scatter<<<T_TOK / 256, 256, 0, stream>>>(tokExp, tokW, cursor, pairTok, pairW, invMap);
    k_cvt_x<<<(T_TOK * H_DIM / 4) / 256, 256, 0, stream>>>(x, xbf);
    k_cvt_w<<<(E_NUM * 2 * I_DIM * H_DIM / 4) / 256, 256, 0, stream>>>(w1, w1bf, w1s, 21);
    k_cvt_w<<<(E_NUM * H_DIM * I_DIM / 4) / 256, 256, 0, stream>>>(w2, w2bf, w2s, 20);

    dim3 g1(MAX_MT, I_DIM / 128);         // 264 x 8
    k_gemm1<<<g1, 512, 0, stream>>>(xbf, w1bf, pairTok, offsets, tileOff, hbuf);
    dim3 g2(MAX_MT, H_DIM / 256);         // 264 x 4
    k_gemm2<<<g2, 512, 0, stream>>>(hbuf, w2bf, pairW, offsets, tileOff, ybuf);
    k_reduce<<<T_TOK, 256, 0, stream>>>(ybuf, invMap, out);
}